// Round 3
// baseline (99.646 us; speedup 1.0000x reference)
//
#include <hip/hip_runtime.h>

#define NPOS 1024
#define D 8

// Single fused dispatch. One block per batch row; 1024 threads, one position
// per thread. Each block redundantly folds the affine weight chain
// (delta = ((sig@W_sig+b)@W_v..@W_o..@W_out..) collapses to a 72-float vector
// since softmax over a single key == 1), then per-position signature terms +
// block-wide inclusive scan.
__global__ __launch_bounds__(1024) void sig_fused(
    const float* __restrict__ feat,
    const float* __restrict__ W_sig, const float* __restrict__ b_sig,
    const float* __restrict__ W_v,   const float* __restrict__ b_v,
    const float* __restrict__ W_o,   const float* __restrict__ b_o,
    const float* __restrict__ W_out, const float* __restrict__ b_out,
    float* __restrict__ out)
{
    __shared__ float u1[64];     // W_o @ W_out
    __shared__ float uu[64];     // W_v @ u1
    __shared__ float w2s[64];    // rows 8..71 of W_sig @ uu  (8x8)
    __shared__ float w1s[8];     // rows 0..7  of W_sig @ uu
    __shared__ float dc[2];      // dc[0]=d (full bias fold), dc[1]=c (t=0 value)
    __shared__ float wtot[16];   // per-wave scan totals

    const int tid = threadIdx.x;
    const int b   = blockIdx.x;
    const float* __restrict__ frow = feat + (size_t)b * NPOS * D;

    // ---- issue feature loads first; they fly during the weight fold ----
    const int sn = (tid < NPOS - 1) ? (tid + 1) : tid;
    float4 p0 = *reinterpret_cast<const float4*>(frow + tid * D);
    float4 p1 = *reinterpret_cast<const float4*>(frow + tid * D + 4);
    float4 n0 = *reinterpret_cast<const float4*>(frow + sn * D);
    float4 n1 = *reinterpret_cast<const float4*>(frow + sn * D + 4);
    float4 z0 = *reinterpret_cast<const float4*>(frow);
    float4 z1 = *reinterpret_cast<const float4*>(frow + 4);

    // ---- weight fold, float4 loads (weights L1/L2-resident across blocks) ----
    if (tid < 64) {
        const float4* __restrict__ Wr = reinterpret_cast<const float4*>(W_o + tid * 64);
        const float4* __restrict__ xr = reinterpret_cast<const float4*>(W_out);
        float s = 0.f;
#pragma unroll
        for (int j = 0; j < 16; ++j) {
            float4 w = Wr[j], x = xr[j];
            s += w.x * x.x + w.y * x.y + w.z * x.z + w.w * x.w;
        }
        u1[tid] = s;
    }
    __syncthreads();
    if (tid < 64) {
        const float4* __restrict__ Wr = reinterpret_cast<const float4*>(W_v + tid * 64);
        const float4* __restrict__ xr = reinterpret_cast<const float4*>(u1);
        float s = 0.f;
#pragma unroll
        for (int j = 0; j < 16; ++j) {
            float4 w = Wr[j], x = xr[j];
            s += w.x * x.x + w.y * x.y + w.z * x.z + w.w * x.w;
        }
        uu[tid] = s;
    } else if (tid == 64) {
        // c = b_out + b_o.W_out + b_v.u1
        const float4* __restrict__ bo = reinterpret_cast<const float4*>(b_o);
        const float4* __restrict__ bv = reinterpret_cast<const float4*>(b_v);
        const float4* __restrict__ wo = reinterpret_cast<const float4*>(W_out);
        const float4* __restrict__ uf = reinterpret_cast<const float4*>(u1);
        float c = b_out[0];
#pragma unroll
        for (int j = 0; j < 16; ++j) {
            float4 a = bo[j], w = wo[j], v = bv[j], u = uf[j];
            c += a.x * w.x + a.y * w.y + a.z * w.z + a.w * w.w
               + v.x * u.x + v.y * u.y + v.z * u.z + v.w * u.w;
        }
        dc[1] = c;
    }
    __syncthreads();
    if (tid < 72) {
        const float4* __restrict__ Wr = reinterpret_cast<const float4*>(W_sig + tid * 64);
        const float4* __restrict__ xr = reinterpret_cast<const float4*>(uu);
        float s = 0.f;
#pragma unroll
        for (int j = 0; j < 16; ++j) {
            float4 w = Wr[j], x = xr[j];
            s += w.x * x.x + w.y * x.y + w.z * x.z + w.w * x.w;
        }
        if (tid < 8) w1s[tid] = s;
        else         w2s[tid - 8] = s;
    } else if (tid == 72) {
        // d = c + b_sig.uu
        const float4* __restrict__ bs = reinterpret_cast<const float4*>(b_sig);
        const float4* __restrict__ uf = reinterpret_cast<const float4*>(uu);
        float dd = dc[1];
#pragma unroll
        for (int j = 0; j < 16; ++j) {
            float4 a = bs[j], u = uf[j];
            dd += a.x * u.x + a.y * u.y + a.z * u.z + a.w * u.w;
        }
        dc[0] = dd;
    }
    __syncthreads();

    // ---- per-position term: g = (f[s]-f0)^T W2 (f[s+1]-f[s]), dv = (f[s+1]-f0).w1 ----
    float fs[D] = {p0.x, p0.y, p0.z, p0.w, p1.x, p1.y, p1.z, p1.w};
    float fn[D] = {n0.x, n0.y, n0.z, n0.w, n1.x, n1.y, n1.z, n1.w};
    float f0[D] = {z0.x, z0.y, z0.z, z0.w, z1.x, z1.y, z1.z, z1.w};

    float gi = 0.f, dv = 0.f;
    if (tid < NPOS - 1) {
        float inc[D];
#pragma unroll
        for (int k = 0; k < D; ++k) inc[k] = fn[k] - fs[k];
#pragma unroll
        for (int r = 0; r < D; ++r) {
            float acc = 0.f;
#pragma unroll
            for (int j = 0; j < D; ++j) acc += w2s[r * D + j] * inc[j];
            gi += (fs[r] - f0[r]) * acc;
        }
#pragma unroll
        for (int k = 0; k < D; ++k) dv += (fn[k] - f0[k]) * w1s[k];
    }

    // ---- inclusive scan across 1024 threads ----
    const int lane = tid & 63;
    const int wave = tid >> 6;
    float t = gi;
#pragma unroll
    for (int off = 1; off < 64; off <<= 1) {
        float nv = __shfl_up(t, off);
        if (lane >= off) t += nv;
    }
    if (lane == 63) wtot[wave] = t;
    __syncthreads();
    float base = 0.f;
#pragma unroll
    for (int w = 0; w < 16; ++w)
        if (w < wave) base += wtot[w];

    // ---- write ----
    float* __restrict__ orow = out + (size_t)b * NPOS;
    if (tid == 0) orow[0] = dc[1];
    if (tid < NPOS - 1) orow[tid + 1] = dv + base + t + dc[0];
}

extern "C" void kernel_launch(void* const* d_in, const int* in_sizes, int n_in,
                              void* d_out, int out_size, void* d_ws, size_t ws_size,
                              hipStream_t stream) {
    const float* features = (const float*)d_in[0];
    const float* W_sig    = (const float*)d_in[1];
    const float* b_sig    = (const float*)d_in[2];
    // d_in[3..8] = W_feat, b_feat, W_q, b_q, W_k, b_k  -- dead (softmax over one key == 1)
    const float* W_v      = (const float*)d_in[9];
    const float* b_v      = (const float*)d_in[10];
    const float* W_o      = (const float*)d_in[11];
    const float* b_o      = (const float*)d_in[12];
    const float* W_out    = (const float*)d_in[13];
    const float* b_out    = (const float*)d_in[14];

    float* o = (float*)d_out;
    sig_fused<<<512, 1024, 0, stream>>>(features, W_sig, b_sig, W_v, b_v,
                                        W_o, b_o, W_out, b_out, o);
}